// Round 1
// baseline (57.984 us; speedup 1.0000x reference)
//
#include <hip/hip_runtime.h>
#include <hip/hip_bf16.h>
#include <math.h>

#define NB_TASKS 20
#define CLASSES_PER_TASK 100
#define N_COLS (NB_TASKS * CLASSES_PER_TASK)   // 2000
#define INV_TEMP (1.0f / 5.0f)

__global__ __launch_bounds__(256) void mix_kernel(
    const float* __restrict__ gol,     // [B, 20]
    const float* __restrict__ gocls,   // [B, 2000]
    const float* __restrict__ dol,     // [B, 2000]
    const float* __restrict__ alpha_p, // [1]
    float* __restrict__ out)           // [B, 2000]
{
    const int b    = blockIdx.x;
    const int tid  = threadIdx.x;
    const int wave = tid >> 6;
    const int lane = tid & 63;

    __shared__ float s_gocl[NB_TASKS];
    __shared__ float s_w[NB_TASKS];

    const float* grow = gocls + (size_t)b * N_COLS;

    // --- per-task max over 100 classes: wave w handles tasks 5w..5w+4 ---
    #pragma unroll
    for (int k = 0; k < 5; ++k) {
        const int t = wave * 5 + k;
        const float* tp = grow + t * CLASSES_PER_TASK;
        float m = tp[lane];                       // lane 0..63 < 100
        if (lane < CLASSES_PER_TASK - 64)         // lanes 0..35 cover 64..99
            m = fmaxf(m, tp[64 + lane]);
        #pragma unroll
        for (int off = 32; off; off >>= 1)
            m = fmaxf(m, __shfl_xor(m, off));
        if (lane == 0) s_gocl[t] = m;
    }
    __syncthreads();

    // --- thread 0: softmax + top-2 for both paths, build weight table ---
    if (tid == 0) {
        const float a = alpha_p[0];
        float w[NB_TASKS];
        #pragma unroll
        for (int t = 0; t < NB_TASKS; ++t) w[t] = 0.0f;

        const float* gr = gol + (size_t)b * NB_TASKS;

        for (int path = 0; path < 2; ++path) {
            const float coef = (path == 0) ? a : (1.0f - a);
            float x[NB_TASKS];
            #pragma unroll
            for (int t = 0; t < NB_TASKS; ++t)
                x[t] = (path == 0) ? gr[t] : s_gocl[t];

            // argmax (first occurrence on tie == top_k tie rule)
            float m1 = x[0]; int i1 = 0;
            #pragma unroll
            for (int t = 1; t < NB_TASKS; ++t)
                if (x[t] > m1) { m1 = x[t]; i1 = t; }

            // softmax(x / T) with max subtraction
            float sum = 0.0f, e[NB_TASKS];
            #pragma unroll
            for (int t = 0; t < NB_TASKS; ++t) {
                e[t] = __expf((x[t] - m1) * INV_TEMP);
                sum += e[t];
            }
            // second argmax, excluding i1
            float m2 = -INFINITY; int i2 = 0;
            #pragma unroll
            for (int t = 0; t < NB_TASKS; ++t)
                if (t != i1 && x[t] > m2) { m2 = x[t]; i2 = t; }

            const float inv = 1.0f / sum;
            w[i1] += coef * e[i1] * inv;
            w[i2] += coef * e[i2] * inv;
        }
        #pragma unroll
        for (int t = 0; t < NB_TASKS; ++t) s_w[t] = w[t];
    }
    __syncthreads();

    // --- output: 500 float4 per row; skip do_logit load where weight==0 ---
    const float4* din  = (const float4*)(dol + (size_t)b * N_COLS);
    float4*       dout = (float4*)(out + (size_t)b * N_COLS);

    for (int f = tid; f < N_COLS / 4; f += 256) {
        const float wgt = s_w[f / (CLASSES_PER_TASK / 4)];  // f/25 -> task
        float4 r;
        if (wgt != 0.0f) {
            float4 v = din[f];
            r.x = v.x * wgt; r.y = v.y * wgt; r.z = v.z * wgt; r.w = v.w * wgt;
        } else {
            r.x = r.y = r.z = r.w = 0.0f;
        }
        dout[f] = r;
    }
}

extern "C" void kernel_launch(void* const* d_in, const int* in_sizes, int n_in,
                              void* d_out, int out_size, void* d_ws, size_t ws_size,
                              hipStream_t stream) {
    const float* gol   = (const float*)d_in[0];
    const float* gocls = (const float*)d_in[1];
    const float* dol   = (const float*)d_in[2];
    const float* alpha = (const float*)d_in[3];
    float* out = (float*)d_out;

    const int B = in_sizes[0] / NB_TASKS;  // 8192

    hipLaunchKernelGGL(mix_kernel, dim3(B), dim3(256), 0, stream,
                       gol, gocls, dol, alpha, out);
}

// Round 2
// 31.176 us; speedup vs baseline: 1.8599x; 1.8599x over previous
//
#include <hip/hip_runtime.h>
#include <hip/hip_bf16.h>
#include <math.h>

#define NB_TASKS 20
#define CLASSES_PER_TASK 100
#define N_COLS (NB_TASKS * CLASSES_PER_TASK)   // 2000
#define INV_TEMP (1.0f / 5.0f)
#define ROWS_PER_BLOCK 4

__global__ __launch_bounds__(256) void mix_kernel(
    const float* __restrict__ gol,     // [B, 20]
    const float* __restrict__ gocls,   // [B, 2000]
    const float* __restrict__ dol,     // [B, 2000]
    const float* __restrict__ alpha_p, // [1]
    float* __restrict__ out,           // [B, 2000]
    int B)
{
    const int tid  = threadIdx.x;
    const int wave = tid >> 6;
    const int lane = tid & 63;
    const int b    = blockIdx.x * ROWS_PER_BLOCK + wave;
    if (b >= B) return;

    const float* grow = gocls + (size_t)b * N_COLS;

    // --- per-task max over 100 classes; lane t ends holding task t's max ---
    float cv = -INFINITY;
    #pragma unroll
    for (int t = 0; t < NB_TASKS; ++t) {
        const float* tp = grow + t * CLASSES_PER_TASK;
        float m = tp[lane];                         // 256 B coalesced
        if (lane < CLASSES_PER_TASK - 64)           // lanes 0..35 cover 64..99
            m = fmaxf(m, tp[64 + lane]);
        #pragma unroll
        for (int off = 32; off; off >>= 1)
            m = fmaxf(m, __shfl_xor(m, off));       // result in all lanes
        if (lane == t) cv = m;
    }

    // gol value for this lane's task
    float gv = (lane < NB_TASKS) ? gol[(size_t)b * NB_TASKS + lane] : -INFINITY;

    const float a = alpha_p[0];

    // --- both paths: wave-parallel softmax + top-2; lane t accumulates w[t] ---
    float wsum = 0.0f;
    #pragma unroll
    for (int path = 0; path < 2; ++path) {
        const float v    = (path == 0) ? gv : cv;
        const float coef = (path == 0) ? a  : (1.0f - a);

        // argmax, min-index tiebreak (== top_k tie rule); all lanes get result
        float v1 = v; int j1 = lane;
        #pragma unroll
        for (int off = 32; off; off >>= 1) {
            float ov = __shfl_xor(v1, off);
            int   oj = __shfl_xor(j1, off);
            if (ov > v1 || (ov == v1 && oj < j1)) { v1 = ov; j1 = oj; }
        }

        // exp((x - max)/T) and its wave sum
        float ex  = (lane < NB_TASKS) ? __expf((v - v1) * INV_TEMP) : 0.0f;
        float sum = ex;
        #pragma unroll
        for (int off = 32; off; off >>= 1)
            sum += __shfl_xor(sum, off);

        // second argmax, excluding j1
        float v2 = (lane == j1) ? -INFINITY : v;
        int   j2 = lane;
        #pragma unroll
        for (int off = 32; off; off >>= 1) {
            float ov = __shfl_xor(v2, off);
            int   oj = __shfl_xor(j2, off);
            if (ov > v2 || (ov == v2 && oj < j2)) { v2 = ov; j2 = oj; }
        }

        // top-2 weights: e[j1]=1 folded into ex at lane j1, e[j2]=ex at lane j2
        if (lane == j1 || lane == j2)
            wsum += coef * ex * (1.0f / sum);
    }
    // lanes >= NB_TASKS have wsum == 0 (j1, j2 always < NB_TASKS)

    // --- output: 500 float4; weight fetched via dynamic shuffle (bpermute) ---
    const float4* din  = (const float4*)(dol + (size_t)b * N_COLS);
    float4*       dout = (float4*)(out + (size_t)b * N_COLS);

    #pragma unroll
    for (int i = 0; i < (N_COLS / 4 + 63) / 64; ++i) {
        const int f = lane + 64 * i;
        if (f < N_COLS / 4) {
            const float wgt = __shfl(wsum, f / (CLASSES_PER_TASK / 4)); // f/25 -> task
            float4 r;
            if (wgt != 0.0f) {
                float4 v = din[f];
                r.x = v.x * wgt; r.y = v.y * wgt; r.z = v.z * wgt; r.w = v.w * wgt;
            } else {
                r.x = r.y = r.z = r.w = 0.0f;
            }
            dout[f] = r;
        }
    }
}

extern "C" void kernel_launch(void* const* d_in, const int* in_sizes, int n_in,
                              void* d_out, int out_size, void* d_ws, size_t ws_size,
                              hipStream_t stream) {
    const float* gol   = (const float*)d_in[0];
    const float* gocls = (const float*)d_in[1];
    const float* dol   = (const float*)d_in[2];
    const float* alpha = (const float*)d_in[3];
    float* out = (float*)d_out;

    const int B = in_sizes[0] / NB_TASKS;  // 8192

    const int grid = (B + ROWS_PER_BLOCK - 1) / ROWS_PER_BLOCK;
    hipLaunchKernelGGL(mix_kernel, dim3(grid), dim3(256), 0, stream,
                       gol, gocls, dol, alpha, out, B);
}

// Round 3
// 28.178 us; speedup vs baseline: 2.0578x; 1.1064x over previous
//
#include <hip/hip_runtime.h>
#include <hip/hip_bf16.h>
#include <math.h>

#define NB_TASKS 20
#define CLASSES_PER_TASK 100
#define N_COLS (NB_TASKS * CLASSES_PER_TASK)   // 2000
#define INV_TEMP (1.0f / 5.0f)
#define ROWS_PER_BLOCK 4

__device__ __forceinline__ float rfl_f(float x) {
    return __int_as_float(__builtin_amdgcn_readfirstlane(__float_as_int(x)));
}

struct Top2 { int j1, j2; float w1, w2; };

// v: lane t (t<20) holds value for task t; lanes 20..63 hold -INF.
// Returns wave-uniform top-2 indices and softmax weights (scaled by coef).
__device__ __forceinline__ Top2 softmax_top2(float v, float coef, int lane) {
    // argmax, min-index tiebreak (== jax top_k tie rule). 5 steps: data in lanes 0..31.
    float v1 = v; int i1 = lane;
    #pragma unroll
    for (int off = 16; off; off >>= 1) {
        float ov = __shfl_xor(v1, off);
        int   oj = __shfl_xor(i1, off);
        if (ov > v1 || (ov == v1 && oj < i1)) { v1 = ov; i1 = oj; }
    }
    // second argmax, excluding lane i1
    float v2 = (lane == i1) ? -INFINITY : v;
    int   i2 = lane;
    #pragma unroll
    for (int off = 16; off; off >>= 1) {
        float ov = __shfl_xor(v2, off);
        int   oj = __shfl_xor(i2, off);
        if (ov > v2 || (ov == v2 && oj < i2)) { v2 = ov; i2 = oj; }
    }
    // softmax denominator: exp((v - max)/T); lanes with v=-INF contribute 0
    float ex  = __expf((v - v1) * INV_TEMP);
    float sum = ex;
    #pragma unroll
    for (int off = 16; off; off >>= 1)
        sum += __shfl_xor(sum, off);

    Top2 r;
    r.j1 = __builtin_amdgcn_readfirstlane(i1);   // lane 0 (lower half) is correct
    r.j2 = __builtin_amdgcn_readfirstlane(i2);
    float w1 = coef / sum;                        // exp(0) = 1
    float w2 = __expf((v2 - v1) * INV_TEMP) * w1;
    r.w1 = rfl_f(w1);
    r.w2 = rfl_f(w2);
    return r;
}

__global__ __launch_bounds__(256) void mix_kernel(
    const float* __restrict__ gol,     // [B, 20]
    const float* __restrict__ gocls,   // [B, 2000]
    const float* __restrict__ dol,     // [B, 2000]
    const float* __restrict__ alpha_p, // [1]
    float* __restrict__ out,           // [B, 2000]
    int B)
{
    const int tid  = threadIdx.x;
    const int lane = tid & 63;
    const int b    = blockIdx.x * ROWS_PER_BLOCK + (tid >> 6);
    if (b >= B) return;

    const int grp = lane >> 4;   // 16-lane group: 0..3
    const int s   = lane & 15;

    const float* grow = gocls + (size_t)b * N_COLS;

    // early uniform/small loads
    const float a  = alpha_p[0];
    const float gv = (lane < NB_TASKS) ? gol[(size_t)b * NB_TASKS + lane] : -INFINITY;

    // --- per-task max over 100 classes, 4 tasks per iteration ---
    // group g handles task 4k+g; 25 float4 per task: lanes read [s] and [16+s] (s<9)
    float cv = -INFINITY;
    #pragma unroll
    for (int k = 0; k < 5; ++k) {
        const float4* p = (const float4*)(grow + (4 * k + grp) * CLASSES_PER_TASK);
        float4 v0 = p[s];
        float m = fmaxf(fmaxf(v0.x, v0.y), fmaxf(v0.z, v0.w));
        if (s < 25 - 16) {
            float4 v1 = p[16 + s];
            m = fmaxf(m, fmaxf(fmaxf(v1.x, v1.y), fmaxf(v1.z, v1.w)));
        }
        #pragma unroll
        for (int off = 8; off; off >>= 1)          // butterfly within 16-lane group
            m = fmaxf(m, __shfl_xor(m, off));
        float g2 = __shfl(m, (lane & 3) << 4);     // lane 4k+g <- group g's max
        if ((lane >> 2) == k) cv = g2;             // lanes 0..19 collect task maxes
    }

    // --- both paths: wave-uniform top-2 weights ---
    const Top2 pa = softmax_top2(gv, a,        lane);
    const Top2 pb = softmax_top2(cv, 1.0f - a, lane);

    // --- output: 500 float4; weight via scalar index compares, skip loads at w==0 ---
    const float4* din  = (const float4*)(dol + (size_t)b * N_COLS);
    float4*       dout = (float4*)(out + (size_t)b * N_COLS);

    #pragma unroll
    for (int i = 0; i < (N_COLS / 4 + 63) / 64; ++i) {
        const int f = lane + 64 * i;
        if (f < N_COLS / 4) {
            const int task = f / (CLASSES_PER_TASK / 4);   // f/25
            float wgt = 0.0f;
            wgt += (task == pa.j1) ? pa.w1 : 0.0f;
            wgt += (task == pa.j2) ? pa.w2 : 0.0f;
            wgt += (task == pb.j1) ? pb.w1 : 0.0f;
            wgt += (task == pb.j2) ? pb.w2 : 0.0f;
            float4 r;
            if (wgt != 0.0f) {
                float4 v = din[f];
                r.x = v.x * wgt; r.y = v.y * wgt; r.z = v.z * wgt; r.w = v.w * wgt;
            } else {
                r.x = r.y = r.z = r.w = 0.0f;
            }
            dout[f] = r;
        }
    }
}

extern "C" void kernel_launch(void* const* d_in, const int* in_sizes, int n_in,
                              void* d_out, int out_size, void* d_ws, size_t ws_size,
                              hipStream_t stream) {
    const float* gol   = (const float*)d_in[0];
    const float* gocls = (const float*)d_in[1];
    const float* dol   = (const float*)d_in[2];
    const float* alpha = (const float*)d_in[3];
    float* out = (float*)d_out;

    const int B = in_sizes[0] / NB_TASKS;  // 8192

    const int grid = (B + ROWS_PER_BLOCK - 1) / ROWS_PER_BLOCK;
    hipLaunchKernelGGL(mix_kernel, dim3(grid), dim3(256), 0, stream,
                       gol, gocls, dol, alpha, out, B);
}